// Round 5
// baseline (325.408 us; speedup 1.0000x reference)
//
#include <hip/hip_runtime.h>
#include <stdint.h>

#define Q_IN 33152
#define NTILES 1160   // 8 chunks x 145 tiles (1 linear + 144 quad)
#define TPC 145

typedef _Float16 half8 __attribute__((ext_vector_type(8)));
typedef float floatx4 __attribute__((ext_vector_type(4)));
typedef uint32_t uint4v __attribute__((ext_vector_type(4)));

// ---------------------------------------------------------------------------
// Tile table in EXECUTION order, chunk-major: T = kch*145 + tt.
// tt=0: linear segment (i0=-1, jb=32*kch). tt>=1: quad tile Q = kch*144+tt-1,
// group-major (g, jt) with jb = 32*(g+jt), inner s=0..31, i0 = 32g+s.
__global__ void build_tab(uint32_t* tab) {
  int T = blockIdx.x * 256 + threadIdx.x;
  if (T >= NTILES) return;
  int kch = T / TPC, tt = T % TPC;
  int i0, jb;
  if (tt == 0) { i0 = -1; jb = 32 * kch; }
  else {
    int Q = kch * 144 + (tt - 1);
    int grp = Q >> 5, s = Q & 31;
    int g = 0, base = 0;
    for (; g < 8; ++g) { int cnt = 8 - g; if (grp < base + cnt) break; base += cnt; }
    int jt = grp - base;
    i0 = 32 * g + s;
    jb = 32 * (g + jt);
  }
  tab[T] = (((uint32_t)(uint16_t)(short)i0) << 16) | (uint32_t)(uint16_t)jb;
}

// ---------------------------------------------------------------------------
// W (f32 [Oreal x Q_IN]) -> f16 MFMA-fragment-tiled Wt, tiles in exec order.
__global__ void convert_w(const float* __restrict__ W, _Float16* __restrict__ Wt,
                          const uint32_t* __restrict__ tab, int NTT, int Oreal) {
  int tid = blockIdx.x * 256 + threadIdx.x;
  if (tid >= NTILES * NTT * 64) return;
  int l = tid & 63;
  int nt = (tid >> 6) % NTT;
  int T = tid / (64 * NTT);
  int o = nt * 16 + (l & 15);
  int koff = (l >> 4) * 8;
  half8 v;
#pragma unroll
  for (int t = 0; t < 8; ++t) v[t] = (_Float16)0.f;
  if (o < Oreal) {
    uint32_t e = tab[T];
    int i0 = (short)(e >> 16);
    int jb = (int)(e & 0xFFFFu);
    const float* row = W + (size_t)o * Q_IN;
    if (i0 < 0) {
#pragma unroll
      for (int t = 0; t < 8; ++t) v[t] = (_Float16)row[jb + koff + t];
    } else {
      int qb = 256 + i0 * 256 - (i0 * (i0 - 1)) / 2 - i0;  // q = qb + j
#pragma unroll
      for (int t = 0; t < 8; ++t) {
        int j = jb + koff + t;
        if (j >= i0) v[t] = (_Float16)row[qb + j];
      }
    }
  }
  *(half8*)(Wt + (size_t)(T * NTT + nt) * 512 + l * 8) = v;
}

// ---------------------------------------------------------------------------
__global__ void init_out(const float* __restrict__ b0, const float* __restrict__ b1,
                         const float* __restrict__ b2, float* __restrict__ h1,
                         float* __restrict__ h2, float* __restrict__ out) {
  int tid = blockIdx.x * 256 + threadIdx.x;
  int b = tid >> 8, o = tid & 255;
  h1[tid] = b0[o];
  h2[tid] = b1[o];
  if (o < 10) out[b * 10 + o] = b2[o];
}

__device__ inline floatx4 mfma16(half8 a, half8 b, floatx4 c) {
  return __builtin_amdgcn_mfma_f32_16x16x32_f16(a, b, c, 0, 0, 0);
}

__device__ inline half8 splat_mul(half8 a, uint32_t sdw, uint32_t sel) {
  uint32_t w = __builtin_amdgcn_perm(sdw, sdw, sel);  // 16-bit broadcast, 1 VALU
  uint4v wv = {w, w, w, w};
  return a * __builtin_bit_cast(half8, wv);           // 4x v_pk_mul_f16, shared src
}

// 1024-thread hT staging: 128 rows x 256 cols f32 -> f16, swizzle ^(row&7)<<4
__device__ inline void stage_hT(_Float16* hT, const float* __restrict__ hIn,
                                int rb, int tid) {
  int r = tid >> 3, sg = tid & 7;
  const float* src = hIn + (size_t)(rb * 128 + r) * 256 + sg * 32;
  char* dst = (char*)hT + r * 512;
  int xo = (r & 7) << 4;
#pragma unroll
  for (int oc = 0; oc < 4; ++oc) {
    float4 f0 = *(const float4*)(src + oc * 8);
    float4 f1 = *(const float4*)(src + oc * 8 + 4);
    half8 hv;
    hv[0] = (_Float16)f0.x; hv[1] = (_Float16)f0.y;
    hv[2] = (_Float16)f0.z; hv[3] = (_Float16)f0.w;
    hv[4] = (_Float16)f1.x; hv[5] = (_Float16)f1.y;
    hv[6] = (_Float16)f1.z; hv[7] = (_Float16)f1.w;
    *(half8*)(dst + ((sg * 64 + oc * 16) ^ xo)) = hv;
  }
}

// ---------------------------------------------------------------------------
// Main quadratic GEMM (layers 0/1): BM=128, N=256, 16 waves (2M x 8N),
// per-wave 64x32 (MT=4, NTW=2). 4 waves/SIMD for latency hiding. A-octets +
// scales in registers; B global->reg, 2-group pipeline, no barriers in loop.
__global__ __launch_bounds__(1024, 4) void qgemm_main(
    const float* __restrict__ hIn, const _Float16* __restrict__ Wt,
    float* __restrict__ outp, const uint32_t* __restrict__ gtab) {
  __shared__ _Float16 hT[128 * 256];     // 64 KB, 512 B/row, XOR-swizzled cols

  const int tid = threadIdx.x;
  const int l = tid & 63;
  const int wid = tid >> 6;        // 0..15
  const int wn = wid & 7;          // column slice (32 cols)
  const int wm = wid >> 3;         // row half (64 rows)
  const int kch = blockIdx.x & 7;  // same-chunk WGs share an XCD (L2-resident Wt)
  const int rb = blockIdx.x >> 3;
  const int tbase = kch * TPC;

  const char* gb = (const char*)Wt + (size_t)tbase * 16384;
  const uint32_t lo = (uint32_t)(wn * 2048 + l * 16);

  // issue linear-tile B + block-0 groups up front
  half8 blin0 = *(const half8*)(gb + lo);
  half8 blin1 = *(const half8*)(gb + (lo + 1024));
  const char* gq = gb + 16384;           // quad tiles start
  half8 gA[4][2], gB[4][2];
#pragma unroll
  for (int sp = 0; sp < 4; ++sp) {
    gA[sp][0] = *(const half8*)(gq + (lo + sp * 16384u));
    gA[sp][1] = *(const half8*)(gq + (lo + sp * 16384u + 1024u));
  }
#pragma unroll
  for (int sp = 0; sp < 4; ++sp) {
    gB[sp][0] = *(const half8*)(gq + (lo + (4 + sp) * 16384u));
    gB[sp][1] = *(const half8*)(gq + (lo + (4 + sp) * 16384u + 1024u));
  }

  stage_hT(hT, hIn, rb, tid);
  __syncthreads();

  floatx4 acc[4][2];
#pragma unroll
  for (int mt = 0; mt < 4; ++mt)
#pragma unroll
    for (int nt = 0; nt < 2; ++nt)
#pragma unroll
      for (int rg = 0; rg < 4; ++rg) acc[mt][nt][rg] = 0.f;

  int rowb[4];
#pragma unroll
  for (int mt = 0; mt < 4; ++mt)
    rowb[mt] = (wm * 64 + mt * 16 + (l & 15)) * 512;
  const int xorb = (l & 7) << 4;
  const int koffA = (l >> 4) * 16;
  const char* hTb = (const char*)hT;

  half8 a[4];
  int prevjb;

  // ---- tile 0: linear (scale = 1) ----
  {
    uint32_t e0 = gtab[tbase];
    int jb = (int)(e0 & 0xFFFFu);
#pragma unroll
    for (int mt = 0; mt < 4; ++mt)
      a[mt] = *(const half8*)(hTb + rowb[mt] + ((jb * 2 + koffA) ^ xorb));
#pragma unroll
    for (int mt = 0; mt < 4; ++mt) {
      acc[mt][0] = mfma16(a[mt], blin0, acc[mt][0]);
      acc[mt][1] = mfma16(a[mt], blin1, acc[mt][1]);
    }
    prevjb = jb;
  }

  // ---- 18 blocks of 8 quad tiles; 2-group register pipeline ----
  uint32_t e = gtab[tbase + 1];
  for (int b = 0; b < 18; ++b) {
    uint32_t enext = (b < 17) ? gtab[tbase + 1 + (b + 1) * 8] : 0u;
    int i0b = (int)(e >> 16);        // block-start i0 (multiple of 8)
    int jb = (int)(e & 0xFFFFu);
    uint4v scu[4];
#pragma unroll
    for (int mt = 0; mt < 4; ++mt)
      scu[mt] = *(const uint4v*)(hTb + rowb[mt] + ((i0b * 2) ^ xorb));
    if (jb != prevjb) {
      prevjb = jb;
#pragma unroll
      for (int mt = 0; mt < 4; ++mt)
        a[mt] = *(const half8*)(hTb + rowb[mt] + ((jb * 2 + koffA) ^ xorb));
    }
    const char* gqn = gq + 131072;

    // consume A-group (tiles 0-3)
#pragma unroll
    for (int sp = 0; sp < 4; ++sp) {
      uint32_t sel = (sp & 1) ? 0x03020302u : 0x01000100u;
#pragma unroll
      for (int mt = 0; mt < 4; ++mt) {
        half8 as_ = splat_mul(a[mt], scu[mt][sp >> 1], sel);
        acc[mt][0] = mfma16(as_, gA[sp][0], acc[mt][0]);
        acc[mt][1] = mfma16(as_, gA[sp][1], acc[mt][1]);
      }
    }
    if (b < 17) {
#pragma unroll
      for (int sp = 0; sp < 4; ++sp) {
        gA[sp][0] = *(const half8*)(gqn + (lo + sp * 16384u));
        gA[sp][1] = *(const half8*)(gqn + (lo + sp * 16384u + 1024u));
      }
    }
    // consume B-group (tiles 4-7)
#pragma unroll
    for (int sp = 0; sp < 4; ++sp) {
      int s = 4 + sp;
      uint32_t sel = (s & 1) ? 0x03020302u : 0x01000100u;
#pragma unroll
      for (int mt = 0; mt < 4; ++mt) {
        half8 as_ = splat_mul(a[mt], scu[mt][s >> 1], sel);
        acc[mt][0] = mfma16(as_, gB[sp][0], acc[mt][0]);
        acc[mt][1] = mfma16(as_, gB[sp][1], acc[mt][1]);
      }
    }
    if (b < 17) {
#pragma unroll
      for (int sp = 0; sp < 4; ++sp) {
        gB[sp][0] = *(const half8*)(gqn + (lo + (4 + sp) * 16384u));
        gB[sp][1] = *(const half8*)(gqn + (lo + (4 + sp) * 16384u + 1024u));
      }
    }
    gq = gqn;
    e = enext;
  }

  // ---- epilogue: split-K atomic accumulate ----
  const int r0 = rb * 128 + wm * 64;
  const int c0 = wn * 32;
#pragma unroll
  for (int mt = 0; mt < 4; ++mt) {
    int rbase = r0 + mt * 16 + (l >> 4) * 4;
#pragma unroll
    for (int nt = 0; nt < 2; ++nt) {
      int c = c0 + nt * 16 + (l & 15);
#pragma unroll
      for (int rg = 0; rg < 4; ++rg)
        atomicAdd(&outp[(size_t)(rbase + rg) * 256 + c], acc[mt][nt][rg]);
    }
  }
}

// ---------------------------------------------------------------------------
// Layer 2 (O=10): 16 waves = 8 row-waves x 2 K-halves; B global->reg.
__global__ __launch_bounds__(1024, 4) void qgemm_small(
    const float* __restrict__ hIn, const _Float16* __restrict__ Wt,
    float* __restrict__ outp, const uint32_t* __restrict__ gtab) {
  __shared__ _Float16 hT[128 * 256];
  const int tid = threadIdx.x;
  const int l = tid & 63;
  const int wid = tid >> 6;
  const int wr = wid & 7;    // row slice (16 rows)
  const int wk = wid >> 3;   // K half
  const int kch = blockIdx.x & 7;
  const int rb = blockIdx.x >> 3;
  const int tbase = kch * TPC;

  stage_hT(hT, hIn, rb, tid);
  __syncthreads();

  floatx4 acc;
#pragma unroll
  for (int rg = 0; rg < 4; ++rg) acc[rg] = 0.f;

  const int rowb = (wr * 16 + (l & 15)) * 512;
  const int xorb = (l & 7) << 4;
  const int koffA = (l >> 4) * 16;
  const char* hTb = (const char*)hT;

  half8 a, sc;
  int prevjb = -1;

  if (wk == 0) {  // linear tile
    uint32_t e0 = gtab[tbase];
    int jb = (int)(e0 & 0xFFFFu);
    a = *(const half8*)(hTb + rowb + ((jb * 2 + koffA) ^ xorb));
    half8 b = *(const half8*)(Wt + (size_t)tbase * 512 + l * 8);
    acc = mfma16(a, b, acc);
    prevjb = jb;
  }

  for (int u8 = wk * 9; u8 < wk * 9 + 9; ++u8) {
    uint32_t e = gtab[tbase + 1 + u8 * 8];
    int i0b = (int)(e >> 16);
    int jb = (int)(e & 0xFFFFu);
    const int ttb = tbase + 1 + u8 * 8;
    half8 bq[8];
#pragma unroll
    for (int s = 0; s < 8; ++s)
      bq[s] = *(const half8*)(Wt + (size_t)(ttb + s) * 512 + l * 8);
    if (jb != prevjb) {
      prevjb = jb;
      a = *(const half8*)(hTb + rowb + ((jb * 2 + koffA) ^ xorb));
    }
    sc = *(const half8*)(hTb + rowb + ((i0b * 2) ^ xorb));
#pragma unroll
    for (int s = 0; s < 8; ++s) {
      _Float16 sv = sc[s];
      half8 sb = {sv, sv, sv, sv, sv, sv, sv, sv};
      acc = mfma16(a * sb, bq[s], acc);
    }
  }

  const int r0 = rb * 128 + wr * 16 + (l >> 4) * 4;
  const int c = l & 15;
  if (c < 10) {
#pragma unroll
    for (int rg = 0; rg < 4; ++rg)
      atomicAdd(&outp[(size_t)(r0 + rg) * 10 + c], acc[rg]);
  }
}

// ---------------------------------------------------------------------------
extern "C" void kernel_launch(void* const* d_in, const int* in_sizes, int n_in,
                              void* d_out, int out_size, void* d_ws, size_t ws_size,
                              hipStream_t stream) {
  const float* x = (const float*)d_in[0];
  const float* W0 = (const float*)d_in[1];
  const float* b0 = (const float*)d_in[2];
  const float* W1 = (const float*)d_in[3];
  const float* b1 = (const float*)d_in[4];
  const float* W2 = (const float*)d_in[5];
  const float* b2 = (const float*)d_in[6];
  float* out = (float*)d_out;

  char* ws = (char*)d_ws;
  float* h1 = (float*)ws;                                  // 4 MB
  float* h2 = (float*)(ws + (4u << 20));                   // 4 MB
  _Float16* Wt = (_Float16*)(ws + (8u << 20));             // 19,005,440 B
  uint32_t* tab = (uint32_t*)(ws + (8u << 20) + 19005440u);

  build_tab<<<(NTILES + 255) / 256, 256, 0, stream>>>(tab);
  init_out<<<4096, 256, 0, stream>>>(b0, b1, b2, h1, h2, out);

  // layer 0
  convert_w<<<(NTILES * 16 * 64) / 256, 256, 0, stream>>>(W0, Wt, tab, 16, 256);
  qgemm_main<<<256, 1024, 0, stream>>>(x, Wt, h1, tab);
  // layer 1
  convert_w<<<(NTILES * 16 * 64) / 256, 256, 0, stream>>>(W1, Wt, tab, 16, 256);
  qgemm_main<<<256, 1024, 0, stream>>>(h1, Wt, h2, tab);
  // layer 2
  convert_w<<<(NTILES * 1 * 64 + 255) / 256, 256, 0, stream>>>(W2, Wt, tab, 1, 10);
  qgemm_small<<<256, 1024, 0, stream>>>(h2, Wt, out, tab);
}

// Round 6
// 311.615 us; speedup vs baseline: 1.0443x; 1.0443x over previous
//
#include <hip/hip_runtime.h>
#include <stdint.h>

#define Q_IN 33152
#define NCH 16
#define TPC 73          // 1 linear-or-pad + 72 quad tiles per chunk
#define NTILES (NCH * TPC)   // 1168

typedef _Float16 half8 __attribute__((ext_vector_type(8)));
typedef float floatx4 __attribute__((ext_vector_type(4)));
typedef uint32_t uint4v __attribute__((ext_vector_type(4)));

// ---------------------------------------------------------------------------
// Tile table, exec order, chunk-major: T = kch*73 + tt.
// tt=0: kch<8 -> linear segment (i0=-1, jb=32*kch); kch>=8 -> pad (i0=-3, B=0).
// tt>=1: quad tile Q = kch*72 + tt-1 of the global 1152; group-major (g,jt)
// with jb = 32*(g+jt), inner s=0..31, i0 = 32g+s. Blocks of 8 stay within a
// group (72 % 8 == 0), so block-start i0 is 8-aligned and jb block-constant.
__global__ void build_tab(uint32_t* tab) {
  int T = blockIdx.x * 256 + threadIdx.x;
  if (T >= NTILES) return;
  int kch = T / TPC, tt = T % TPC;
  int i0, jb;
  if (tt == 0) {
    if (kch < 8) { i0 = -1; jb = 32 * kch; }
    else         { i0 = -3; jb = 0; }
  } else {
    int Q = kch * 72 + (tt - 1);
    int grp = Q >> 5, s = Q & 31;
    int g = 0, base = 0;
    for (; g < 8; ++g) { int cnt = 8 - g; if (grp < base + cnt) break; base += cnt; }
    int jt = grp - base;
    i0 = 32 * g + s;
    jb = 32 * (g + jt);
  }
  tab[T] = (((uint32_t)(uint16_t)(short)i0) << 16) | (uint32_t)(uint16_t)jb;
}

// ---------------------------------------------------------------------------
// W (f32 [Oreal x Q_IN]) -> f16 MFMA-fragment-tiled Wt, tiles in exec order.
// i0==-3 (pad) leaves zeros.
__global__ void convert_w(const float* __restrict__ W, _Float16* __restrict__ Wt,
                          const uint32_t* __restrict__ tab, int NTT, int Oreal) {
  int tid = blockIdx.x * 256 + threadIdx.x;
  if (tid >= NTILES * NTT * 64) return;
  int l = tid & 63;
  int nt = (tid >> 6) % NTT;
  int T = tid / (64 * NTT);
  int o = nt * 16 + (l & 15);
  int koff = (l >> 4) * 8;
  half8 v;
#pragma unroll
  for (int t = 0; t < 8; ++t) v[t] = (_Float16)0.f;
  if (o < Oreal) {
    uint32_t e = tab[T];
    int i0 = (short)(e >> 16);
    int jb = (int)(e & 0xFFFFu);
    const float* row = W + (size_t)o * Q_IN;
    if (i0 == -1) {
#pragma unroll
      for (int t = 0; t < 8; ++t) v[t] = (_Float16)row[jb + koff + t];
    } else if (i0 >= 0) {
      int qb = 256 + i0 * 256 - (i0 * (i0 - 1)) / 2 - i0;  // q = qb + j
#pragma unroll
      for (int t = 0; t < 8; ++t) {
        int j = jb + koff + t;
        if (j >= i0) v[t] = (_Float16)row[qb + j];
      }
    }
  }
  *(half8*)(Wt + (size_t)(T * NTT + nt) * 512 + l * 8) = v;
}

// ---------------------------------------------------------------------------
__global__ void init_out(const float* __restrict__ b0, const float* __restrict__ b1,
                         const float* __restrict__ b2, float* __restrict__ h1,
                         float* __restrict__ h2, float* __restrict__ out) {
  int tid = blockIdx.x * 256 + threadIdx.x;
  int b = tid >> 8, o = tid & 255;
  h1[tid] = b0[o];
  h2[tid] = b1[o];
  if (o < 10) out[b * 10 + o] = b2[o];
}

__device__ inline floatx4 mfma16(half8 a, half8 b, floatx4 c) {
  return __builtin_amdgcn_mfma_f32_16x16x32_f16(a, b, c, 0, 0, 0);
}

__device__ inline half8 splat_mul(half8 a, uint32_t sdw, uint32_t sel) {
  uint32_t w = __builtin_amdgcn_perm(sdw, sdw, sel);  // 16-bit broadcast, 1 VALU
  uint4v wv = {w, w, w, w};
  return a * __builtin_bit_cast(half8, wv);           // 4x v_pk_mul_f16, shared src
}

// ---------------------------------------------------------------------------
// Main quadratic GEMM (layers 0/1): BM=128, N=256, 8 waves (1M x 8N),
// per-wave 128x32 (MT=8, NTW=2). Grid 512 = 16 K-chunks x 32 row-blocks ->
// 2 WGs/CU, 4 waves/SIMD. A-octets + scales in registers; B global->reg,
// 2-group pipeline, NO barriers in the K-loop. (Same codegen as the 89 us
// R4 kernel; only the chunk geometry changed.)
__global__ __launch_bounds__(512, 2) void qgemm_main(
    const float* __restrict__ hIn, const _Float16* __restrict__ Wt,
    float* __restrict__ outp, const uint32_t* __restrict__ gtab) {
  __shared__ _Float16 hT[128 * 256];     // 64 KB, 512 B/row, XOR-swizzled cols

  const int tid = threadIdx.x;
  const int l = tid & 63;
  const int wid = tid >> 6;
  const int kch = blockIdx.x & 15;  // chunks c, c+8 share an XCD (L2-resident Wt)
  const int rb = blockIdx.x >> 4;
  const int tbase = kch * TPC;

  // uniform (SGPR) B base + 32-bit lane offset -> saddr-form global loads
  const char* gb = (const char*)Wt + (size_t)tbase * 16384;
  const uint32_t lo = (uint32_t)(wid * 2048 + l * 16);

  // issue tile-0 B + block-0 groups up front (latency hides under staging)
  half8 blin0 = *(const half8*)(gb + lo);
  half8 blin1 = *(const half8*)(gb + (lo + 1024));
  const char* gq = gb + 16384;           // quad tiles start
  half8 gA[4][2], gB[4][2];
#pragma unroll
  for (int sp = 0; sp < 4; ++sp) {
    gA[sp][0] = *(const half8*)(gq + (lo + sp * 16384u));
    gA[sp][1] = *(const half8*)(gq + (lo + sp * 16384u + 1024u));
  }
#pragma unroll
  for (int sp = 0; sp < 4; ++sp) {
    gB[sp][0] = *(const half8*)(gq + (lo + (4 + sp) * 16384u));
    gB[sp][1] = *(const half8*)(gq + (lo + (4 + sp) * 16384u + 1024u));
  }

  // ---- stage h tile (f32 -> f16, swizzle byte^=(row&7)<<4) ----
  {
    int r = tid >> 2, sg = tid & 3;
    const float* src = hIn + (size_t)(rb * 128 + r) * 256 + sg * 64;
    char* dst = (char*)hT + r * 512;
    int xo = (r & 7) << 4;
#pragma unroll
    for (int oc = 0; oc < 8; ++oc) {
      float4 f0 = *(const float4*)(src + oc * 8);
      float4 f1 = *(const float4*)(src + oc * 8 + 4);
      half8 hv;
      hv[0] = (_Float16)f0.x; hv[1] = (_Float16)f0.y;
      hv[2] = (_Float16)f0.z; hv[3] = (_Float16)f0.w;
      hv[4] = (_Float16)f1.x; hv[5] = (_Float16)f1.y;
      hv[6] = (_Float16)f1.z; hv[7] = (_Float16)f1.w;
      *(half8*)(dst + ((sg * 128 + oc * 16) ^ xo)) = hv;
    }
  }
  __syncthreads();

  floatx4 acc[8][2];
#pragma unroll
  for (int mt = 0; mt < 8; ++mt)
#pragma unroll
    for (int nt = 0; nt < 2; ++nt)
#pragma unroll
      for (int rg = 0; rg < 4; ++rg) acc[mt][nt][rg] = 0.f;

  int rowb[8];
#pragma unroll
  for (int mt = 0; mt < 8; ++mt) rowb[mt] = (mt * 16 + (l & 15)) * 512;
  const int xorb = (l & 7) << 4;
  const int koffA = (l >> 4) * 16;
  const char* hTb = (const char*)hT;

  half8 a[8];
  int prevjb;

  // ---- tile 0: linear (scale = 1); pad chunks have B == 0 ----
  {
    uint32_t e0 = gtab[tbase];
    int jb = (int)(e0 & 0xFFFFu);
#pragma unroll
    for (int mt = 0; mt < 8; ++mt)
      a[mt] = *(const half8*)(hTb + rowb[mt] + ((jb * 2 + koffA) ^ xorb));
#pragma unroll
    for (int mt = 0; mt < 8; ++mt) {
      acc[mt][0] = mfma16(a[mt], blin0, acc[mt][0]);
      acc[mt][1] = mfma16(a[mt], blin1, acc[mt][1]);
    }
    prevjb = jb;
  }

  // ---- 9 blocks of 8 quad tiles; 2-group register pipeline ----
  uint32_t e = gtab[tbase + 1];
  for (int b = 0; b < 9; ++b) {
    uint32_t enext = (b < 8) ? gtab[tbase + 1 + (b + 1) * 8] : 0u;
    int i0b = (int)(e >> 16);        // block-start i0 (multiple of 8)
    int jb = (int)(e & 0xFFFFu);
    uint4v scu[8];
#pragma unroll
    for (int mt = 0; mt < 8; ++mt)
      scu[mt] = *(const uint4v*)(hTb + rowb[mt] + ((i0b * 2) ^ xorb));
    if (jb != prevjb) {
      prevjb = jb;
#pragma unroll
      for (int mt = 0; mt < 8; ++mt)
        a[mt] = *(const half8*)(hTb + rowb[mt] + ((jb * 2 + koffA) ^ xorb));
    }
    const char* gqn = gq + 131072;

    // consume A-group (tiles 0-3)
#pragma unroll
    for (int sp = 0; sp < 4; ++sp) {
      uint32_t sel = (sp & 1) ? 0x03020302u : 0x01000100u;
#pragma unroll
      for (int mt = 0; mt < 8; ++mt) {
        half8 as_ = splat_mul(a[mt], scu[mt][sp >> 1], sel);
        acc[mt][0] = mfma16(as_, gA[sp][0], acc[mt][0]);
        acc[mt][1] = mfma16(as_, gA[sp][1], acc[mt][1]);
      }
    }
    // refill A-group for next block
    if (b < 8) {
#pragma unroll
      for (int sp = 0; sp < 4; ++sp) {
        gA[sp][0] = *(const half8*)(gqn + (lo + sp * 16384u));
        gA[sp][1] = *(const half8*)(gqn + (lo + sp * 16384u + 1024u));
      }
    }
    // consume B-group (tiles 4-7)
#pragma unroll
    for (int sp = 0; sp < 4; ++sp) {
      int s = 4 + sp;
      uint32_t sel = (s & 1) ? 0x03020302u : 0x01000100u;
#pragma unroll
      for (int mt = 0; mt < 8; ++mt) {
        half8 as_ = splat_mul(a[mt], scu[mt][s >> 1], sel);
        acc[mt][0] = mfma16(as_, gB[sp][0], acc[mt][0]);
        acc[mt][1] = mfma16(as_, gB[sp][1], acc[mt][1]);
      }
    }
    // refill B-group for next block
    if (b < 8) {
#pragma unroll
      for (int sp = 0; sp < 4; ++sp) {
        gB[sp][0] = *(const half8*)(gqn + (lo + (4 + sp) * 16384u));
        gB[sp][1] = *(const half8*)(gqn + (lo + (4 + sp) * 16384u + 1024u));
      }
    }
    gq = gqn;
    e = enext;
  }

  // ---- epilogue: split-K atomic accumulate ----
  const int r0 = rb * 128;
  const int c0 = wid * 32;
#pragma unroll
  for (int mt = 0; mt < 8; ++mt) {
    int rbase = r0 + mt * 16 + (l >> 4) * 4;
#pragma unroll
    for (int nt = 0; nt < 2; ++nt) {
      int c = c0 + nt * 16 + (l & 15);
#pragma unroll
      for (int rg = 0; rg < 4; ++rg)
        atomicAdd(&outp[(size_t)(rbase + rg) * 256 + c], acc[mt][nt][rg]);
    }
  }
}

// ---------------------------------------------------------------------------
// Layer 2 (O=10, one 16-wide n-tile): B global->reg, no barriers in loop.
// Grid 512 = 16 chunks x 32 row-blocks; 8 waves each own 16 rows.
__global__ __launch_bounds__(512, 2) void qgemm_small(
    const float* __restrict__ hIn, const _Float16* __restrict__ Wt,
    float* __restrict__ outp, const uint32_t* __restrict__ gtab) {
  __shared__ _Float16 hT[128 * 256];
  const int tid = threadIdx.x;
  const int l = tid & 63;
  const int wid = tid >> 6;
  const int kch = blockIdx.x & 15;
  const int rb = blockIdx.x >> 4;
  const int tbase = kch * TPC;

  {
    int r = tid >> 2, sg = tid & 3;
    const float* src = hIn + (size_t)(rb * 128 + r) * 256 + sg * 64;
    char* dst = (char*)hT + r * 512;
    int xo = (r & 7) << 4;
#pragma unroll
    for (int oc = 0; oc < 8; ++oc) {
      float4 f0 = *(const float4*)(src + oc * 8);
      float4 f1 = *(const float4*)(src + oc * 8 + 4);
      half8 hv;
      hv[0] = (_Float16)f0.x; hv[1] = (_Float16)f0.y;
      hv[2] = (_Float16)f0.z; hv[3] = (_Float16)f0.w;
      hv[4] = (_Float16)f1.x; hv[5] = (_Float16)f1.y;
      hv[6] = (_Float16)f1.z; hv[7] = (_Float16)f1.w;
      *(half8*)(dst + ((sg * 128 + oc * 16) ^ xo)) = hv;
    }
  }
  __syncthreads();

  floatx4 acc;
#pragma unroll
  for (int rg = 0; rg < 4; ++rg) acc[rg] = 0.f;

  const int rowb = (wid * 16 + (l & 15)) * 512;
  const int xorb = (l & 7) << 4;
  const int koffA = (l >> 4) * 16;
  const char* hTb = (const char*)hT;

  half8 a, sc;
  int prevjb;

  {
    uint32_t e0 = gtab[tbase];
    int jb = (int)(e0 & 0xFFFFu);
    a = *(const half8*)(hTb + rowb + ((jb * 2 + koffA) ^ xorb));
    half8 b = *(const half8*)(Wt + (size_t)tbase * 512 + l * 8);
    acc = mfma16(a, b, acc);
    prevjb = jb;
  }

  for (int u8 = 0; u8 < 9; ++u8) {
    uint32_t e = gtab[tbase + 1 + u8 * 8];
    int i0b = (int)(e >> 16);
    int jb = (int)(e & 0xFFFFu);
    const int ttb = tbase + 1 + u8 * 8;
    half8 bq[8];
#pragma unroll
    for (int s = 0; s < 8; ++s)
      bq[s] = *(const half8*)(Wt + (size_t)(ttb + s) * 512 + l * 8);
    if (jb != prevjb) {
      prevjb = jb;
      a = *(const half8*)(hTb + rowb + ((jb * 2 + koffA) ^ xorb));
    }
    sc = *(const half8*)(hTb + rowb + ((i0b * 2) ^ xorb));
#pragma unroll
    for (int s = 0; s < 8; ++s) {
      _Float16 sv = sc[s];
      half8 sb = {sv, sv, sv, sv, sv, sv, sv, sv};
      acc = mfma16(a * sb, bq[s], acc);
    }
  }

  const int r0 = rb * 128 + wid * 16 + (l >> 4) * 4;
  const int c = l & 15;
  if (c < 10) {
#pragma unroll
    for (int rg = 0; rg < 4; ++rg)
      atomicAdd(&outp[(size_t)(r0 + rg) * 10 + c], acc[rg]);
  }
}

// ---------------------------------------------------------------------------
extern "C" void kernel_launch(void* const* d_in, const int* in_sizes, int n_in,
                              void* d_out, int out_size, void* d_ws, size_t ws_size,
                              hipStream_t stream) {
  const float* x = (const float*)d_in[0];
  const float* W0 = (const float*)d_in[1];
  const float* b0 = (const float*)d_in[2];
  const float* W1 = (const float*)d_in[3];
  const float* b1 = (const float*)d_in[4];
  const float* W2 = (const float*)d_in[5];
  const float* b2 = (const float*)d_in[6];
  float* out = (float*)d_out;

  char* ws = (char*)d_ws;
  float* h1 = (float*)ws;                                  // 4 MB
  float* h2 = (float*)(ws + (4u << 20));                   // 4 MB
  _Float16* Wt = (_Float16*)(ws + (8u << 20));             // 1168*16KB = 19,136,512 B
  uint32_t* tab = (uint32_t*)(ws + (8u << 20) + 19136512u);

  build_tab<<<(NTILES + 255) / 256, 256, 0, stream>>>(tab);
  init_out<<<4096, 256, 0, stream>>>(b0, b1, b2, h1, h2, out);

  // layer 0
  convert_w<<<(NTILES * 16 * 64) / 256, 256, 0, stream>>>(W0, Wt, tab, 16, 256);
  qgemm_main<<<512, 512, 0, stream>>>(x, Wt, h1, tab);
  // layer 1
  convert_w<<<(NTILES * 16 * 64) / 256, 256, 0, stream>>>(W1, Wt, tab, 16, 256);
  qgemm_main<<<512, 512, 0, stream>>>(h1, Wt, h2, tab);
  // layer 2
  convert_w<<<(NTILES * 1 * 64 + 255) / 256, 256, 0, stream>>>(W2, Wt, tab, 1, 10);
  qgemm_small<<<512, 512, 0, stream>>>(h2, Wt, out, tab);
}

// Round 7
// 309.688 us; speedup vs baseline: 1.0508x; 1.0062x over previous
//
#include <hip/hip_runtime.h>
#include <stdint.h>

#define Q_IN 33152
#define NTILES 1160   // 8 chunks x 145 tiles (1 linear + 144 quad)
#define TPC 145

typedef _Float16 half8 __attribute__((ext_vector_type(8)));
typedef float floatx4 __attribute__((ext_vector_type(4)));
typedef uint32_t uint4v __attribute__((ext_vector_type(4)));

// ---------------------------------------------------------------------------
// Tile table in EXECUTION order, chunk-major: T = kch*145 + tt.
// tt=0: linear segment (i0=-1, jb=32*kch). tt>=1: quad tile Q = kch*144+tt-1,
// group-major (g, jt) with jb = 32*(g+jt), inner s=0..31, i0 = 32g+s.
__global__ void build_tab(uint32_t* tab) {
  int T = blockIdx.x * 256 + threadIdx.x;
  if (T >= NTILES) return;
  int kch = T / TPC, tt = T % TPC;
  int i0, jb;
  if (tt == 0) { i0 = -1; jb = 32 * kch; }
  else {
    int Q = kch * 144 + (tt - 1);
    int grp = Q >> 5, s = Q & 31;
    int g = 0, base = 0;
    for (; g < 8; ++g) { int cnt = 8 - g; if (grp < base + cnt) break; base += cnt; }
    int jt = grp - base;
    i0 = 32 * g + s;
    jb = 32 * (g + jt);
  }
  tab[T] = (((uint32_t)(uint16_t)(short)i0) << 16) | (uint32_t)(uint16_t)jb;
}

// ---------------------------------------------------------------------------
// W (f32 [Oreal x Q_IN]) -> f16 MFMA-fragment-tiled Wt, tiles in exec order.
__global__ void convert_w(const float* __restrict__ W, _Float16* __restrict__ Wt,
                          const uint32_t* __restrict__ tab, int NTT, int Oreal) {
  int tid = blockIdx.x * 256 + threadIdx.x;
  if (tid >= NTILES * NTT * 64) return;
  int l = tid & 63;
  int nt = (tid >> 6) % NTT;
  int T = tid / (64 * NTT);
  int o = nt * 16 + (l & 15);
  int koff = (l >> 4) * 8;
  half8 v;
#pragma unroll
  for (int t = 0; t < 8; ++t) v[t] = (_Float16)0.f;
  if (o < Oreal) {
    uint32_t e = tab[T];
    int i0 = (short)(e >> 16);
    int jb = (int)(e & 0xFFFFu);
    const float* row = W + (size_t)o * Q_IN;
    if (i0 < 0) {
#pragma unroll
      for (int t = 0; t < 8; ++t) v[t] = (_Float16)row[jb + koff + t];
    } else {
      int qb = 256 + i0 * 256 - (i0 * (i0 - 1)) / 2 - i0;  // q = qb + j
#pragma unroll
      for (int t = 0; t < 8; ++t) {
        int j = jb + koff + t;
        if (j >= i0) v[t] = (_Float16)row[qb + j];
      }
    }
  }
  *(half8*)(Wt + (size_t)(T * NTT + nt) * 512 + l * 8) = v;
}

// ---------------------------------------------------------------------------
__global__ void init_out(const float* __restrict__ b0, const float* __restrict__ b1,
                         const float* __restrict__ b2, float* __restrict__ h1,
                         float* __restrict__ h2, float* __restrict__ out) {
  int tid = blockIdx.x * 256 + threadIdx.x;
  int b = tid >> 8, o = tid & 255;
  h1[tid] = b0[o];
  h2[tid] = b1[o];
  if (o < 10) out[b * 10 + o] = b2[o];
}

__device__ inline floatx4 mfma16(half8 a, half8 b, floatx4 c) {
  return __builtin_amdgcn_mfma_f32_16x16x32_f16(a, b, c, 0, 0, 0);
}

__device__ inline half8 splat_mul(half8 a, uint32_t sdw, uint32_t sel) {
  uint32_t w = __builtin_amdgcn_perm(sdw, sdw, sel);  // 16-bit broadcast, 1 VALU
  uint4v wv = {w, w, w, w};
  return a * __builtin_bit_cast(half8, wv);           // 4x v_pk_mul_f16, shared src
}

// ---------------------------------------------------------------------------
// Main quadratic GEMM (layers 0/1): BM=64, N=256, 8 waves (1M x 8N),
// per-wave 64x32 (MT=4, NTW=2). Grid 512 = 8 chunks x 64 row-blocks.
// LDS 32KB/WG + <=128 VGPR -> 2 WGs/CU (4 waves/SIMD) for MFMA/VALU overlap.
// A-octets + scales in registers; B global->reg 2-group pipeline, no barriers.
__global__ __launch_bounds__(512, 4) void qgemm_main(
    const float* __restrict__ hIn, const _Float16* __restrict__ Wt,
    float* __restrict__ outp, const uint32_t* __restrict__ gtab) {
  __shared__ _Float16 hT[64 * 256];      // 32 KB, 512 B/row, XOR-swizzled cols

  const int tid = threadIdx.x;
  const int l = tid & 63;
  const int wid = tid >> 6;
  const int kch = blockIdx.x & 7;   // same-chunk WGs share an XCD (L2-resident Wt)
  const int rb = blockIdx.x >> 3;   // 0..63
  const int tbase = kch * TPC;

  // uniform (SGPR) B base + 32-bit lane offset -> saddr-form global loads
  const char* gb = (const char*)Wt + (size_t)tbase * 16384;
  const uint32_t lo = (uint32_t)(wid * 2048 + l * 16);

  // issue linear-tile B + block-0 groups up front (latency hides under staging)
  half8 blin0 = *(const half8*)(gb + lo);
  half8 blin1 = *(const half8*)(gb + (lo + 1024));
  const char* gq = gb + 16384;           // quad tiles start
  half8 gA[4][2], gB[4][2];
#pragma unroll
  for (int sp = 0; sp < 4; ++sp) {
    gA[sp][0] = *(const half8*)(gq + (lo + sp * 16384u));
    gA[sp][1] = *(const half8*)(gq + (lo + sp * 16384u + 1024u));
  }
#pragma unroll
  for (int sp = 0; sp < 4; ++sp) {
    gB[sp][0] = *(const half8*)(gq + (lo + (4 + sp) * 16384u));
    gB[sp][1] = *(const half8*)(gq + (lo + (4 + sp) * 16384u + 1024u));
  }

  // ---- stage h tile: 64 rows x 256 cols f32 -> f16, swizzle ^(row&7)<<4 ----
  {
    int r = tid >> 3, sg = tid & 7;
    const float* src = hIn + (size_t)(rb * 64 + r) * 256 + sg * 32;
    char* dst = (char*)hT + r * 512;
    int xo = (r & 7) << 4;
#pragma unroll
    for (int oc = 0; oc < 4; ++oc) {
      float4 f0 = *(const float4*)(src + oc * 8);
      float4 f1 = *(const float4*)(src + oc * 8 + 4);
      half8 hv;
      hv[0] = (_Float16)f0.x; hv[1] = (_Float16)f0.y;
      hv[2] = (_Float16)f0.z; hv[3] = (_Float16)f0.w;
      hv[4] = (_Float16)f1.x; hv[5] = (_Float16)f1.y;
      hv[6] = (_Float16)f1.z; hv[7] = (_Float16)f1.w;
      *(half8*)(dst + ((sg * 64 + oc * 16) ^ xo)) = hv;
    }
  }
  __syncthreads();

  floatx4 acc[4][2];
#pragma unroll
  for (int mt = 0; mt < 4; ++mt)
#pragma unroll
    for (int nt = 0; nt < 2; ++nt)
#pragma unroll
      for (int rg = 0; rg < 4; ++rg) acc[mt][nt][rg] = 0.f;

  int rowb[4];
#pragma unroll
  for (int mt = 0; mt < 4; ++mt) rowb[mt] = (mt * 16 + (l & 15)) * 512;
  const int xorb = (l & 7) << 4;
  const int koffA = (l >> 4) * 16;
  const char* hTb = (const char*)hT;

  half8 a[4];
  int prevjb;

  // ---- tile 0: linear (scale = 1) ----
  {
    uint32_t e0 = gtab[tbase];
    int jb = (int)(e0 & 0xFFFFu);
#pragma unroll
    for (int mt = 0; mt < 4; ++mt)
      a[mt] = *(const half8*)(hTb + rowb[mt] + ((jb * 2 + koffA) ^ xorb));
#pragma unroll
    for (int mt = 0; mt < 4; ++mt) {
      acc[mt][0] = mfma16(a[mt], blin0, acc[mt][0]);
      acc[mt][1] = mfma16(a[mt], blin1, acc[mt][1]);
    }
    prevjb = jb;
  }

  // ---- 18 blocks of 8 quad tiles; 2-group register pipeline ----
  uint32_t e = gtab[tbase + 1];
  for (int b = 0; b < 18; ++b) {
    uint32_t enext = (b < 17) ? gtab[tbase + 1 + (b + 1) * 8] : 0u;
    int i0b = (int)(e >> 16);        // block-start i0 (multiple of 8)
    int jb = (int)(e & 0xFFFFu);
    uint4v scu[4];
#pragma unroll
    for (int mt = 0; mt < 4; ++mt)
      scu[mt] = *(const uint4v*)(hTb + rowb[mt] + ((i0b * 2) ^ xorb));
    if (jb != prevjb) {
      prevjb = jb;
#pragma unroll
      for (int mt = 0; mt < 4; ++mt)
        a[mt] = *(const half8*)(hTb + rowb[mt] + ((jb * 2 + koffA) ^ xorb));
    }
    const char* gqn = gq + 131072;

    // consume A-group (tiles 0-3)
#pragma unroll
    for (int sp = 0; sp < 4; ++sp) {
      uint32_t sel = (sp & 1) ? 0x03020302u : 0x01000100u;
#pragma unroll
      for (int mt = 0; mt < 4; ++mt) {
        half8 as_ = splat_mul(a[mt], scu[mt][sp >> 1], sel);
        acc[mt][0] = mfma16(as_, gA[sp][0], acc[mt][0]);
        acc[mt][1] = mfma16(as_, gA[sp][1], acc[mt][1]);
      }
    }
    // refill A-group for next block
    if (b < 17) {
#pragma unroll
      for (int sp = 0; sp < 4; ++sp) {
        gA[sp][0] = *(const half8*)(gqn + (lo + sp * 16384u));
        gA[sp][1] = *(const half8*)(gqn + (lo + sp * 16384u + 1024u));
      }
    }
    // consume B-group (tiles 4-7)
#pragma unroll
    for (int sp = 0; sp < 4; ++sp) {
      int s = 4 + sp;
      uint32_t sel = (s & 1) ? 0x03020302u : 0x01000100u;
#pragma unroll
      for (int mt = 0; mt < 4; ++mt) {
        half8 as_ = splat_mul(a[mt], scu[mt][s >> 1], sel);
        acc[mt][0] = mfma16(as_, gB[sp][0], acc[mt][0]);
        acc[mt][1] = mfma16(as_, gB[sp][1], acc[mt][1]);
      }
    }
    // refill B-group for next block
    if (b < 17) {
#pragma unroll
      for (int sp = 0; sp < 4; ++sp) {
        gB[sp][0] = *(const half8*)(gqn + (lo + (4 + sp) * 16384u));
        gB[sp][1] = *(const half8*)(gqn + (lo + (4 + sp) * 16384u + 1024u));
      }
    }
    gq = gqn;
    e = enext;
  }

  // ---- epilogue: split-K atomic accumulate (8-way, as R4) ----
  const int r0 = rb * 64;
  const int c0 = wid * 32;
#pragma unroll
  for (int mt = 0; mt < 4; ++mt) {
    int rbase = r0 + mt * 16 + (l >> 4) * 4;
#pragma unroll
    for (int nt = 0; nt < 2; ++nt) {
      int c = c0 + nt * 16 + (l & 15);
#pragma unroll
      for (int rg = 0; rg < 4; ++rg)
        atomicAdd(&outp[(size_t)(rbase + rg) * 256 + c], acc[mt][nt][rg]);
    }
  }
}

// ---------------------------------------------------------------------------
// Layer 2 (O=10, one 16-wide n-tile): B global->reg, no barriers in loop.
// (Unchanged from the proven R4 version.)
__global__ __launch_bounds__(512, 2) void qgemm_small(
    const float* __restrict__ hIn, const _Float16* __restrict__ Wt,
    float* __restrict__ outp, const uint32_t* __restrict__ gtab) {
  __shared__ _Float16 hT[128 * 256];
  const int tid = threadIdx.x;
  const int l = tid & 63;
  const int wid = tid >> 6;
  const int kch = blockIdx.x & 7;
  const int rb = blockIdx.x >> 3;
  const int tbase = kch * TPC;

  {
    int r = tid >> 2, sg = tid & 3;
    const float* src = hIn + (size_t)(rb * 128 + r) * 256 + sg * 64;
    char* dst = (char*)hT + r * 512;
    int xo = (r & 7) << 4;
#pragma unroll
    for (int oc = 0; oc < 8; ++oc) {
      float4 f0 = *(const float4*)(src + oc * 8);
      float4 f1 = *(const float4*)(src + oc * 8 + 4);
      half8 hv;
      hv[0] = (_Float16)f0.x; hv[1] = (_Float16)f0.y;
      hv[2] = (_Float16)f0.z; hv[3] = (_Float16)f0.w;
      hv[4] = (_Float16)f1.x; hv[5] = (_Float16)f1.y;
      hv[6] = (_Float16)f1.z; hv[7] = (_Float16)f1.w;
      *(half8*)(dst + ((sg * 128 + oc * 16) ^ xo)) = hv;
    }
  }
  __syncthreads();

  floatx4 acc;
#pragma unroll
  for (int rg = 0; rg < 4; ++rg) acc[rg] = 0.f;

  const int rowb = (wid * 16 + (l & 15)) * 512;
  const int xorb = (l & 7) << 4;
  const int koffA = (l >> 4) * 16;
  const char* hTb = (const char*)hT;

  half8 a, sc;
  int prevjb;

  {
    uint32_t e0 = gtab[tbase];
    int jb = (int)(e0 & 0xFFFFu);
    a = *(const half8*)(hTb + rowb + ((jb * 2 + koffA) ^ xorb));
    half8 b = *(const half8*)(Wt + (size_t)tbase * 512 + l * 8);
    acc = mfma16(a, b, acc);
    prevjb = jb;
  }

  for (int u8 = 0; u8 < 18; ++u8) {
    uint32_t e = gtab[tbase + 1 + u8 * 8];
    int i0b = (int)(e >> 16);
    int jb = (int)(e & 0xFFFFu);
    const int ttb = tbase + 1 + u8 * 8;
    half8 bq[8];
#pragma unroll
    for (int s = 0; s < 8; ++s)
      bq[s] = *(const half8*)(Wt + (size_t)(ttb + s) * 512 + l * 8);
    if (jb != prevjb) {
      prevjb = jb;
      a = *(const half8*)(hTb + rowb + ((jb * 2 + koffA) ^ xorb));
    }
    sc = *(const half8*)(hTb + rowb + ((i0b * 2) ^ xorb));
#pragma unroll
    for (int s = 0; s < 8; ++s) {
      _Float16 sv = sc[s];
      half8 sb = {sv, sv, sv, sv, sv, sv, sv, sv};
      acc = mfma16(a * sb, bq[s], acc);
    }
  }

  const int r0 = rb * 128 + wid * 16 + (l >> 4) * 4;
  const int c = l & 15;
  if (c < 10) {
#pragma unroll
    for (int rg = 0; rg < 4; ++rg)
      atomicAdd(&outp[(size_t)(r0 + rg) * 10 + c], acc[rg]);
  }
}

// ---------------------------------------------------------------------------
extern "C" void kernel_launch(void* const* d_in, const int* in_sizes, int n_in,
                              void* d_out, int out_size, void* d_ws, size_t ws_size,
                              hipStream_t stream) {
  const float* x = (const float*)d_in[0];
  const float* W0 = (const float*)d_in[1];
  const float* b0 = (const float*)d_in[2];
  const float* W1 = (const float*)d_in[3];
  const float* b1 = (const float*)d_in[4];
  const float* W2 = (const float*)d_in[5];
  const float* b2 = (const float*)d_in[6];
  float* out = (float*)d_out;

  char* ws = (char*)d_ws;
  float* h1 = (float*)ws;                                  // 4 MB
  float* h2 = (float*)(ws + (4u << 20));                   // 4 MB
  _Float16* Wt = (_Float16*)(ws + (8u << 20));             // 19,005,440 B
  uint32_t* tab = (uint32_t*)(ws + (8u << 20) + 19005440u);

  build_tab<<<(NTILES + 255) / 256, 256, 0, stream>>>(tab);
  init_out<<<4096, 256, 0, stream>>>(b0, b1, b2, h1, h2, out);

  // layer 0
  convert_w<<<(NTILES * 16 * 64) / 256, 256, 0, stream>>>(W0, Wt, tab, 16, 256);
  qgemm_main<<<512, 512, 0, stream>>>(x, Wt, h1, tab);
  // layer 1
  convert_w<<<(NTILES * 16 * 64) / 256, 256, 0, stream>>>(W1, Wt, tab, 16, 256);
  qgemm_main<<<512, 512, 0, stream>>>(h1, Wt, h2, tab);
  // layer 2
  convert_w<<<(NTILES * 1 * 64 + 255) / 256, 256, 0, stream>>>(W2, Wt, tab, 1, 10);
  qgemm_small<<<256, 512, 0, stream>>>(h2, Wt, out, tab);
}

// Round 8
// 307.509 us; speedup vs baseline: 1.0582x; 1.0071x over previous
//
#include <hip/hip_runtime.h>
#include <stdint.h>

#define Q_IN 33152
#define NTILES 1160   // 8 chunks x 145 tiles (1 linear + 144 quad)
#define TPC 145

typedef _Float16 half8 __attribute__((ext_vector_type(8)));
typedef float floatx4 __attribute__((ext_vector_type(4)));
typedef uint32_t uint2v __attribute__((ext_vector_type(2)));
typedef uint32_t uint4v __attribute__((ext_vector_type(4)));

// ---------------------------------------------------------------------------
// Tile table in EXECUTION order, chunk-major: T = kch*145 + tt.
// tt=0: linear segment (i0=-1, jb=32*kch). tt>=1: quad tile Q = kch*144+tt-1,
// group-major (g, jt) with jb = 32*(g+jt), inner s=0..31, i0 = 32g+s.
__global__ void build_tab(uint32_t* tab) {
  int T = blockIdx.x * 256 + threadIdx.x;
  if (T >= NTILES) return;
  int kch = T / TPC, tt = T % TPC;
  int i0, jb;
  if (tt == 0) { i0 = -1; jb = 32 * kch; }
  else {
    int Q = kch * 144 + (tt - 1);
    int grp = Q >> 5, s = Q & 31;
    int g = 0, base = 0;
    for (; g < 8; ++g) { int cnt = 8 - g; if (grp < base + cnt) break; base += cnt; }
    int jt = grp - base;
    i0 = 32 * g + s;
    jb = 32 * (g + jt);
  }
  tab[T] = (((uint32_t)(uint16_t)(short)i0) << 16) | (uint32_t)(uint16_t)jb;
}

// ---------------------------------------------------------------------------
// W (f32 [Oreal x Q_IN]) -> f16 MFMA-fragment-tiled Wt, tiles in exec order.
__global__ void convert_w(const float* __restrict__ W, _Float16* __restrict__ Wt,
                          const uint32_t* __restrict__ tab, int NTT, int Oreal) {
  int tid = blockIdx.x * 256 + threadIdx.x;
  if (tid >= NTILES * NTT * 64) return;
  int l = tid & 63;
  int nt = (tid >> 6) % NTT;
  int T = tid / (64 * NTT);
  int o = nt * 16 + (l & 15);
  int koff = (l >> 4) * 8;
  half8 v;
#pragma unroll
  for (int t = 0; t < 8; ++t) v[t] = (_Float16)0.f;
  if (o < Oreal) {
    uint32_t e = tab[T];
    int i0 = (short)(e >> 16);
    int jb = (int)(e & 0xFFFFu);
    const float* row = W + (size_t)o * Q_IN;
    if (i0 < 0) {
#pragma unroll
      for (int t = 0; t < 8; ++t) v[t] = (_Float16)row[jb + koff + t];
    } else {
      int qb = 256 + i0 * 256 - (i0 * (i0 - 1)) / 2 - i0;  // q = qb + j
#pragma unroll
      for (int t = 0; t < 8; ++t) {
        int j = jb + koff + t;
        if (j >= i0) v[t] = (_Float16)row[qb + j];
      }
    }
  }
  *(half8*)(Wt + (size_t)(T * NTT + nt) * 512 + l * 8) = v;
}

// ---------------------------------------------------------------------------
__global__ void init_out(const float* __restrict__ b0, const float* __restrict__ b1,
                         const float* __restrict__ b2, float* __restrict__ h1,
                         float* __restrict__ h2, float* __restrict__ out) {
  int tid = blockIdx.x * 256 + threadIdx.x;
  int b = tid >> 8, o = tid & 255;
  h1[tid] = b0[o];
  h2[tid] = b1[o];
  if (o < 10) out[b * 10 + o] = b2[o];
}

__device__ inline floatx4 mfma16(half8 a, half8 b, floatx4 c) {
  return __builtin_amdgcn_mfma_f32_16x16x32_f16(a, b, c, 0, 0, 0);
}

__device__ inline half8 splat_mul(half8 a, uint32_t sdw, uint32_t sel) {
  uint32_t w = __builtin_amdgcn_perm(sdw, sdw, sel);  // 16-bit broadcast, 1 VALU
  uint4v wv = {w, w, w, w};
  return a * __builtin_bit_cast(half8, wv);           // 4x v_pk_mul_f16, shared src
}

// ---------------------------------------------------------------------------
// Main quadratic GEMM (layers 0/1): BM=64, N=256, 8 waves (1M x 8N),
// per-wave 64x32 (MT=4, NTW=2). Grid 512 = 8 chunks x 64 row-blocks.
// Register-lean loop (target <=64 arch VGPR + 32 AGPR acc -> 2 WGs/CU,
// 4 waves/SIMD): mt-outer consumption (one A-octet live at a time, A/scales
// re-read from LDS per half-block), B double-buffered at 4-tile granularity
// via saddr-form global->reg loads. No barriers in the K-loop.
__global__ __launch_bounds__(512, 4) void qgemm_main(
    const float* __restrict__ hIn, const _Float16* __restrict__ Wt,
    float* __restrict__ outp, const uint32_t* __restrict__ gtab) {
  __shared__ _Float16 hT[64 * 256];      // 32 KB, 512 B/row, XOR-swizzled cols

  const int tid = threadIdx.x;
  const int l = tid & 63;
  const int wid = tid >> 6;
  const int kch = blockIdx.x & 7;   // same-chunk WGs share an XCD (L2-resident Wt)
  const int rb = blockIdx.x >> 3;   // 0..63
  const int tbase = kch * TPC;

  const char* gb = (const char*)Wt + (size_t)tbase * 16384;
  const char* gq = gb + 16384;           // quad tiles start
  const uint32_t lo = (uint32_t)(wid * 2048 + l * 16);

  const int xorb = (l & 7) << 4;
  const int koffA = (l >> 4) * 16;
  const char* hTb = (const char*)hT;

  half8 bufA[4][2], bufB[4][2];
  uint32_t off = lo;

  auto issue = [&](half8 (&buf)[4][2], uint32_t o) {
#pragma unroll
    for (int sp = 0; sp < 4; ++sp) {
      buf[sp][0] = *(const half8*)(gq + (o + sp * 16384u));
      buf[sp][1] = *(const half8*)(gq + (o + sp * 16384u + 1024u));
    }
  };

  floatx4 acc[4][2];
#pragma unroll
  for (int mt = 0; mt < 4; ++mt)
#pragma unroll
    for (int nt = 0; nt < 2; ++nt)
#pragma unroll
      for (int rg = 0; rg < 4; ++rg) acc[mt][nt][rg] = 0.f;

  // consume one 4-tile half: mt-outer, single A-octet + scale word live
  auto consume = [&](half8 (&buf)[4][2], int jb, int i0b, int h) {
#pragma unroll
    for (int mt = 0; mt < 4; ++mt) {
      int rowb = (mt * 16 + (l & 15)) * 512;
      half8 av = *(const half8*)(hTb + rowb + ((jb * 2 + koffA) ^ xorb));
      uint2v sc2 = *(const uint2v*)(hTb + rowb + ((i0b * 2) ^ xorb) + h * 8);
#pragma unroll
      for (int s = 0; s < 4; ++s) {
        uint32_t sel = (s & 1) ? 0x03020302u : 0x01000100u;
        half8 as_ = splat_mul(av, sc2[s >> 1], sel);
        acc[mt][0] = mfma16(as_, buf[s][0], acc[mt][0]);
        acc[mt][1] = mfma16(as_, buf[s][1], acc[mt][1]);
      }
    }
  };

  // prologue: linear-tile B + first half in flight before staging
  half8 blin0 = *(const half8*)(gb + lo);
  half8 blin1 = *(const half8*)(gb + (lo + 1024));
  issue(bufA, off); off += 65536;

  // ---- stage h tile: 64 rows x 256 cols f32 -> f16, swizzle ^(row&7)<<4 ----
  {
    int r = tid >> 3, sg = tid & 7;
    const float* src = hIn + (size_t)(rb * 64 + r) * 256 + sg * 32;
    char* dst = (char*)hT + r * 512;
    int xo = (r & 7) << 4;
#pragma unroll
    for (int oc = 0; oc < 4; ++oc) {
      float4 f0 = *(const float4*)(src + oc * 8);
      float4 f1 = *(const float4*)(src + oc * 8 + 4);
      half8 hv;
      hv[0] = (_Float16)f0.x; hv[1] = (_Float16)f0.y;
      hv[2] = (_Float16)f0.z; hv[3] = (_Float16)f0.w;
      hv[4] = (_Float16)f1.x; hv[5] = (_Float16)f1.y;
      hv[6] = (_Float16)f1.z; hv[7] = (_Float16)f1.w;
      *(half8*)(dst + ((sg * 64 + oc * 16) ^ xo)) = hv;
    }
  }
  __syncthreads();

  // ---- tile 0: linear (scale = 1) ----
  {
    uint32_t e0 = gtab[tbase];
    int jb = (int)(e0 & 0xFFFFu);
#pragma unroll
    for (int mt = 0; mt < 4; ++mt) {
      int rowb = (mt * 16 + (l & 15)) * 512;
      half8 av = *(const half8*)(hTb + rowb + ((jb * 2 + koffA) ^ xorb));
      acc[mt][0] = mfma16(av, blin0, acc[mt][0]);
      acc[mt][1] = mfma16(av, blin1, acc[mt][1]);
    }
  }

  // ---- 18 blocks = 36 half-blocks; B double-buffer, issue-before-consume ----
  uint32_t e = gtab[tbase + 1];
  for (int b = 0; b < 18; ++b) {
    uint32_t enext = (b < 17) ? gtab[tbase + 1 + (b + 1) * 8] : 0u;
    int i0b = (int)(e >> 16);        // block-start i0 (multiple of 8)
    int jb = (int)(e & 0xFFFFu);
    issue(bufB, off); off += 65536;          // half 1 of this block
    consume(bufA, jb, i0b, 0);
    if (b < 17) { issue(bufA, off); off += 65536; }   // half 0 of next block
    consume(bufB, jb, i0b, 1);
    e = enext;
  }

  // ---- epilogue: split-K atomic accumulate (8-way) ----
  const int r0 = rb * 64;
  const int c0 = wid * 32;
#pragma unroll
  for (int mt = 0; mt < 4; ++mt) {
    int rbase = r0 + mt * 16 + (l >> 4) * 4;
#pragma unroll
    for (int nt = 0; nt < 2; ++nt) {
      int c = c0 + nt * 16 + (l & 15);
#pragma unroll
      for (int rg = 0; rg < 4; ++rg)
        atomicAdd(&outp[(size_t)(rbase + rg) * 256 + c], acc[mt][nt][rg]);
    }
  }
}

// ---------------------------------------------------------------------------
// Layer 2 (O=10, one 16-wide n-tile): B global->reg, no barriers in loop.
// (Proven R4 version.)
__global__ __launch_bounds__(512, 2) void qgemm_small(
    const float* __restrict__ hIn, const _Float16* __restrict__ Wt,
    float* __restrict__ outp, const uint32_t* __restrict__ gtab) {
  __shared__ _Float16 hT[128 * 256];
  const int tid = threadIdx.x;
  const int l = tid & 63;
  const int wid = tid >> 6;
  const int kch = blockIdx.x & 7;
  const int rb = blockIdx.x >> 3;
  const int tbase = kch * TPC;

  {
    int r = tid >> 2, sg = tid & 3;
    const float* src = hIn + (size_t)(rb * 128 + r) * 256 + sg * 64;
    char* dst = (char*)hT + r * 512;
    int xo = (r & 7) << 4;
#pragma unroll
    for (int oc = 0; oc < 8; ++oc) {
      float4 f0 = *(const float4*)(src + oc * 8);
      float4 f1 = *(const float4*)(src + oc * 8 + 4);
      half8 hv;
      hv[0] = (_Float16)f0.x; hv[1] = (_Float16)f0.y;
      hv[2] = (_Float16)f0.z; hv[3] = (_Float16)f0.w;
      hv[4] = (_Float16)f1.x; hv[5] = (_Float16)f1.y;
      hv[6] = (_Float16)f1.z; hv[7] = (_Float16)f1.w;
      *(half8*)(dst + ((sg * 128 + oc * 16) ^ xo)) = hv;
    }
  }
  __syncthreads();

  floatx4 acc;
#pragma unroll
  for (int rg = 0; rg < 4; ++rg) acc[rg] = 0.f;

  const int rowb = (wid * 16 + (l & 15)) * 512;
  const int xorb = (l & 7) << 4;
  const int koffA = (l >> 4) * 16;
  const char* hTb = (const char*)hT;

  half8 a, sc;
  int prevjb;

  {
    uint32_t e0 = gtab[tbase];
    int jb = (int)(e0 & 0xFFFFu);
    a = *(const half8*)(hTb + rowb + ((jb * 2 + koffA) ^ xorb));
    half8 b = *(const half8*)(Wt + (size_t)tbase * 512 + l * 8);
    acc = mfma16(a, b, acc);
    prevjb = jb;
  }

  for (int u8 = 0; u8 < 18; ++u8) {
    uint32_t e = gtab[tbase + 1 + u8 * 8];
    int i0b = (int)(e >> 16);
    int jb = (int)(e & 0xFFFFu);
    const int ttb = tbase + 1 + u8 * 8;
    half8 bq[8];
#pragma unroll
    for (int s = 0; s < 8; ++s)
      bq[s] = *(const half8*)(Wt + (size_t)(ttb + s) * 512 + l * 8);
    if (jb != prevjb) {
      prevjb = jb;
      a = *(const half8*)(hTb + rowb + ((jb * 2 + koffA) ^ xorb));
    }
    sc = *(const half8*)(hTb + rowb + ((i0b * 2) ^ xorb));
#pragma unroll
    for (int s = 0; s < 8; ++s) {
      _Float16 sv = sc[s];
      half8 sb = {sv, sv, sv, sv, sv, sv, sv, sv};
      acc = mfma16(a * sb, bq[s], acc);
    }
  }

  const int r0 = rb * 128 + wid * 16 + (l >> 4) * 4;
  const int c = l & 15;
  if (c < 10) {
#pragma unroll
    for (int rg = 0; rg < 4; ++rg)
      atomicAdd(&outp[(size_t)(r0 + rg) * 10 + c], acc[rg]);
  }
}

// ---------------------------------------------------------------------------
extern "C" void kernel_launch(void* const* d_in, const int* in_sizes, int n_in,
                              void* d_out, int out_size, void* d_ws, size_t ws_size,
                              hipStream_t stream) {
  const float* x = (const float*)d_in[0];
  const float* W0 = (const float*)d_in[1];
  const float* b0 = (const float*)d_in[2];
  const float* W1 = (const float*)d_in[3];
  const float* b1 = (const float*)d_in[4];
  const float* W2 = (const float*)d_in[5];
  const float* b2 = (const float*)d_in[6];
  float* out = (float*)d_out;

  char* ws = (char*)d_ws;
  float* h1 = (float*)ws;                                  // 4 MB
  float* h2 = (float*)(ws + (4u << 20));                   // 4 MB
  _Float16* Wt = (_Float16*)(ws + (8u << 20));             // 19,005,440 B
  uint32_t* tab = (uint32_t*)(ws + (8u << 20) + 19005440u);

  build_tab<<<(NTILES + 255) / 256, 256, 0, stream>>>(tab);
  init_out<<<4096, 256, 0, stream>>>(b0, b1, b2, h1, h2, out);

  // layer 0
  convert_w<<<(NTILES * 16 * 64) / 256, 256, 0, stream>>>(W0, Wt, tab, 16, 256);
  qgemm_main<<<512, 512, 0, stream>>>(x, Wt, h1, tab);
  // layer 1
  convert_w<<<(NTILES * 16 * 64) / 256, 256, 0, stream>>>(W1, Wt, tab, 16, 256);
  qgemm_main<<<512, 512, 0, stream>>>(h1, Wt, h2, tab);
  // layer 2
  convert_w<<<(NTILES * 1 * 64 + 255) / 256, 256, 0, stream>>>(W2, Wt, tab, 1, 10);
  qgemm_small<<<256, 512, 0, stream>>>(h2, Wt, out, tab);
}

// Round 9
// 237.699 us; speedup vs baseline: 1.3690x; 1.2937x over previous
//
#include <hip/hip_runtime.h>
#include <stdint.h>

#define Q_IN 33152
#define NTILES 1160   // 8 chunks x 145 tiles (1 linear + 144 quad)
#define TPC 145

typedef _Float16 half8 __attribute__((ext_vector_type(8)));
typedef float floatx4 __attribute__((ext_vector_type(4)));
typedef uint32_t uint4v __attribute__((ext_vector_type(4)));

// ---------------------------------------------------------------------------
// Tile table in EXECUTION order, chunk-major: T = kch*145 + tt.
// tt=0: linear segment (i0=-1, jb=32*kch). tt>=1: quad tile Q = kch*144+tt-1,
// group-major (g, jt) with jb = 32*(g+jt), inner s=0..31, i0 = 32g+s.
__global__ void build_tab(uint32_t* tab) {
  int T = blockIdx.x * 256 + threadIdx.x;
  if (T >= NTILES) return;
  int kch = T / TPC, tt = T % TPC;
  int i0, jb;
  if (tt == 0) { i0 = -1; jb = 32 * kch; }
  else {
    int Q = kch * 144 + (tt - 1);
    int grp = Q >> 5, s = Q & 31;
    int g = 0, base = 0;
    for (; g < 8; ++g) { int cnt = 8 - g; if (grp < base + cnt) break; base += cnt; }
    int jt = grp - base;
    i0 = 32 * g + s;
    jb = 32 * (g + jt);
  }
  tab[T] = (((uint32_t)(uint16_t)(short)i0) << 16) | (uint32_t)(uint16_t)jb;
}

// ---------------------------------------------------------------------------
// W (f32 [Oreal x Q_IN]) -> f16 MFMA-fragment-tiled Wt, tiles in exec order.
__global__ void convert_w(const float* __restrict__ W, _Float16* __restrict__ Wt,
                          const uint32_t* __restrict__ tab, int NTT, int Oreal) {
  int tid = blockIdx.x * 256 + threadIdx.x;
  if (tid >= NTILES * NTT * 64) return;
  int l = tid & 63;
  int nt = (tid >> 6) % NTT;
  int T = tid / (64 * NTT);
  int o = nt * 16 + (l & 15);
  int koff = (l >> 4) * 8;
  half8 v;
#pragma unroll
  for (int t = 0; t < 8; ++t) v[t] = (_Float16)0.f;
  if (o < Oreal) {
    uint32_t e = tab[T];
    int i0 = (short)(e >> 16);
    int jb = (int)(e & 0xFFFFu);
    const float* row = W + (size_t)o * Q_IN;
    if (i0 < 0) {
#pragma unroll
      for (int t = 0; t < 8; ++t) v[t] = (_Float16)row[jb + koff + t];
    } else {
      int qb = 256 + i0 * 256 - (i0 * (i0 - 1)) / 2 - i0;  // q = qb + j
#pragma unroll
      for (int t = 0; t < 8; ++t) {
        int j = jb + koff + t;
        if (j >= i0) v[t] = (_Float16)row[qb + j];
      }
    }
  }
  *(half8*)(Wt + (size_t)(T * NTT + nt) * 512 + l * 8) = v;
}

// ---------------------------------------------------------------------------
// reduce partials + bias -> h  (4096 x 256 f32), float4 vectorized
__global__ void reduce_h(const float* __restrict__ part, const float* __restrict__ bias,
                         float* __restrict__ h) {
  int t = blockIdx.x * 256 + threadIdx.x;     // 262144 threads, 1 float4 each
  float4 acc = *(const float4*)(bias + ((t & 63) << 2));
#pragma unroll
  for (int k = 0; k < 8; ++k) {
    float4 p = *(const float4*)(part + (size_t)k * 1048576 + t * 4);
    acc.x += p.x; acc.y += p.y; acc.z += p.z; acc.w += p.w;
  }
  *(float4*)(h + t * 4) = acc;
}

// reduce partials + bias -> out (4096 x 10), part2 stride 16
__global__ void reduce_out(const float* __restrict__ part2, const float* __restrict__ b2,
                           float* __restrict__ out) {
  int t = blockIdx.x * 256 + threadIdx.x;     // 40960
  if (t >= 40960) return;
  int b = t / 10, o = t - b * 10;
  float acc = b2[o];
#pragma unroll
  for (int k = 0; k < 8; ++k) acc += part2[(size_t)k * 65536 + b * 16 + o];
  out[t] = acc;
}

__device__ inline floatx4 mfma16(half8 a, half8 b, floatx4 c) {
  return __builtin_amdgcn_mfma_f32_16x16x32_f16(a, b, c, 0, 0, 0);
}

// a * broadcast(lo/hi half of s) via v_pk_mul_f16 op_sel (no v_perm needed)
__device__ inline half8 splat_mul_lo(half8 a, uint32_t s) {
  uint4v av = __builtin_bit_cast(uint4v, a), r;
#pragma unroll
  for (int k = 0; k < 4; ++k)
    asm("v_pk_mul_f16 %0, %1, %2 op_sel:[0,0] op_sel_hi:[1,0]"
        : "=v"(r[k]) : "v"(av[k]), "v"(s));
  return __builtin_bit_cast(half8, r);
}
__device__ inline half8 splat_mul_hi(half8 a, uint32_t s) {
  uint4v av = __builtin_bit_cast(uint4v, a), r;
#pragma unroll
  for (int k = 0; k < 4; ++k)
    asm("v_pk_mul_f16 %0, %1, %2 op_sel:[0,1] op_sel_hi:[1,1]"
        : "=v"(r[k]) : "v"(av[k]), "v"(s));
  return __builtin_bit_cast(half8, r);
}

// ---------------------------------------------------------------------------
// Main quadratic GEMM (layers 0/1): BM=128, N=256, 8 waves (1M x 8N),
// per-wave 128x32 (MT=8, NTW=2). A-octets + scales in registers (hoisted per
// jb-group / per 8-s block). B global->reg 2-group pipeline, no barriers.
// Epilogue: plain stores to this chunk's private partial buffer (no atomics).
__global__ __launch_bounds__(512, 1) void qgemm_main(
    const float* __restrict__ hIn, const _Float16* __restrict__ Wt,
    float* __restrict__ part, const uint32_t* __restrict__ gtab) {
  __shared__ _Float16 hT[128 * 256];     // 64 KB, 512 B/row, XOR-swizzled cols

  const int tid = threadIdx.x;
  const int l = tid & 63;
  const int wid = tid >> 6;
  const int kch = blockIdx.x & 7;   // same-chunk WGs share an XCD (L2-resident Wt)
  const int rb = blockIdx.x >> 3;
  const int tbase = kch * TPC;

  const char* gb = (const char*)Wt + (size_t)tbase * 16384;
  const uint32_t lo = (uint32_t)(wid * 2048 + l * 16);

  // issue linear-tile B + block-0 groups up front (latency hides under staging)
  half8 blin0 = *(const half8*)(gb + lo);
  half8 blin1 = *(const half8*)(gb + (lo + 1024));
  const char* gq = gb + 16384;           // quad tiles start
  half8 gA[4][2], gB[4][2];
#pragma unroll
  for (int sp = 0; sp < 4; ++sp) {
    gA[sp][0] = *(const half8*)(gq + (lo + sp * 16384u));
    gA[sp][1] = *(const half8*)(gq + (lo + sp * 16384u + 1024u));
  }
#pragma unroll
  for (int sp = 0; sp < 4; ++sp) {
    gB[sp][0] = *(const half8*)(gq + (lo + (4 + sp) * 16384u));
    gB[sp][1] = *(const half8*)(gq + (lo + (4 + sp) * 16384u + 1024u));
  }

  // ---- stage h tile (f32 -> f16, swizzle byte^=(row&7)<<4) ----
  {
    int r = tid >> 2, sg = tid & 3;
    const float* src = hIn + (size_t)(rb * 128 + r) * 256 + sg * 64;
    char* dst = (char*)hT + r * 512;
    int xo = (r & 7) << 4;
#pragma unroll
    for (int oc = 0; oc < 8; ++oc) {
      float4 f0 = *(const float4*)(src + oc * 8);
      float4 f1 = *(const float4*)(src + oc * 8 + 4);
      half8 hv;
      hv[0] = (_Float16)f0.x; hv[1] = (_Float16)f0.y;
      hv[2] = (_Float16)f0.z; hv[3] = (_Float16)f0.w;
      hv[4] = (_Float16)f1.x; hv[5] = (_Float16)f1.y;
      hv[6] = (_Float16)f1.z; hv[7] = (_Float16)f1.w;
      *(half8*)(dst + ((sg * 128 + oc * 16) ^ xo)) = hv;
    }
  }
  __syncthreads();

  floatx4 acc[8][2];
#pragma unroll
  for (int mt = 0; mt < 8; ++mt)
#pragma unroll
    for (int nt = 0; nt < 2; ++nt)
#pragma unroll
      for (int rg = 0; rg < 4; ++rg) acc[mt][nt][rg] = 0.f;

  int rowb[8];
#pragma unroll
  for (int mt = 0; mt < 8; ++mt) rowb[mt] = (mt * 16 + (l & 15)) * 512;
  const int xorb = (l & 7) << 4;
  const int koffA = (l >> 4) * 16;
  const char* hTb = (const char*)hT;

  half8 a[8];
  int prevjb;

  // ---- tile 0: linear (scale = 1) ----
  {
    uint32_t e0 = gtab[tbase];
    int jb = (int)(e0 & 0xFFFFu);
#pragma unroll
    for (int mt = 0; mt < 8; ++mt)
      a[mt] = *(const half8*)(hTb + rowb[mt] + ((jb * 2 + koffA) ^ xorb));
#pragma unroll
    for (int mt = 0; mt < 8; ++mt) {
      acc[mt][0] = mfma16(a[mt], blin0, acc[mt][0]);
      acc[mt][1] = mfma16(a[mt], blin1, acc[mt][1]);
    }
    prevjb = jb;
  }

  // ---- 18 blocks of 8 quad tiles; 2-group register pipeline ----
  uint32_t e = gtab[tbase + 1];
  for (int b = 0; b < 18; ++b) {
    uint32_t enext = (b < 17) ? gtab[tbase + 1 + (b + 1) * 8] : 0u;
    int i0b = (int)(e >> 16);        // block-start i0 (multiple of 8)
    int jb = (int)(e & 0xFFFFu);
    uint4v scu[8];
#pragma unroll
    for (int mt = 0; mt < 8; ++mt)
      scu[mt] = *(const uint4v*)(hTb + rowb[mt] + ((i0b * 2) ^ xorb));
    if (jb != prevjb) {
      prevjb = jb;
#pragma unroll
      for (int mt = 0; mt < 8; ++mt)
        a[mt] = *(const half8*)(hTb + rowb[mt] + ((jb * 2 + koffA) ^ xorb));
    }
    const char* gqn = gq + 131072;

    // consume A-group (tiles 0-3)
#pragma unroll
    for (int sp = 0; sp < 4; ++sp) {
#pragma unroll
      for (int mt = 0; mt < 8; ++mt) {
        half8 as_ = (sp & 1) ? splat_mul_hi(a[mt], scu[mt][sp >> 1])
                             : splat_mul_lo(a[mt], scu[mt][sp >> 1]);
        acc[mt][0] = mfma16(as_, gA[sp][0], acc[mt][0]);
        acc[mt][1] = mfma16(as_, gA[sp][1], acc[mt][1]);
      }
    }
    if (b < 17) {
#pragma unroll
      for (int sp = 0; sp < 4; ++sp) {
        gA[sp][0] = *(const half8*)(gqn + (lo + sp * 16384u));
        gA[sp][1] = *(const half8*)(gqn + (lo + sp * 16384u + 1024u));
      }
    }
    // consume B-group (tiles 4-7)
#pragma unroll
    for (int sp = 0; sp < 4; ++sp) {
#pragma unroll
      for (int mt = 0; mt < 8; ++mt) {
        half8 as_ = (sp & 1) ? splat_mul_hi(a[mt], scu[mt][2 + (sp >> 1)])
                             : splat_mul_lo(a[mt], scu[mt][2 + (sp >> 1)]);
        acc[mt][0] = mfma16(as_, gB[sp][0], acc[mt][0]);
        acc[mt][1] = mfma16(as_, gB[sp][1], acc[mt][1]);
      }
    }
    if (b < 17) {
#pragma unroll
      for (int sp = 0; sp < 4; ++sp) {
        gB[sp][0] = *(const half8*)(gqn + (lo + (4 + sp) * 16384u));
        gB[sp][1] = *(const half8*)(gqn + (lo + (4 + sp) * 16384u + 1024u));
      }
    }
    gq = gqn;
    e = enext;
  }

  // ---- epilogue: plain stores to this chunk's partial buffer ----
  float* op = part + (size_t)kch * 1048576;
  const int r0 = rb * 128;
  const int c0 = wid * 32;
#pragma unroll
  for (int mt = 0; mt < 8; ++mt) {
    int rbase = r0 + mt * 16 + (l >> 4) * 4;
#pragma unroll
    for (int nt = 0; nt < 2; ++nt) {
      int c = c0 + nt * 16 + (l & 15);
#pragma unroll
      for (int rg = 0; rg < 4; ++rg)
        op[(size_t)(rbase + rg) * 256 + c] = acc[mt][nt][rg];
    }
  }
}

// ---------------------------------------------------------------------------
// Layer 2 (O=10, one 16-wide n-tile): B global->reg, no barriers in loop.
// Stores to 16-wide padded partials (cols >=10 are exact zeros from padded W).
__global__ __launch_bounds__(512, 2) void qgemm_small(
    const float* __restrict__ hIn, const _Float16* __restrict__ Wt,
    float* __restrict__ part2, const uint32_t* __restrict__ gtab) {
  __shared__ _Float16 hT[128 * 256];
  const int tid = threadIdx.x;
  const int l = tid & 63;
  const int wid = tid >> 6;
  const int kch = blockIdx.x & 7;
  const int rb = blockIdx.x >> 3;
  const int tbase = kch * TPC;

  {
    int r = tid >> 2, sg = tid & 3;
    const float* src = hIn + (size_t)(rb * 128 + r) * 256 + sg * 64;
    char* dst = (char*)hT + r * 512;
    int xo = (r & 7) << 4;
#pragma unroll
    for (int oc = 0; oc < 8; ++oc) {
      float4 f0 = *(const float4*)(src + oc * 8);
      float4 f1 = *(const float4*)(src + oc * 8 + 4);
      half8 hv;
      hv[0] = (_Float16)f0.x; hv[1] = (_Float16)f0.y;
      hv[2] = (_Float16)f0.z; hv[3] = (_Float16)f0.w;
      hv[4] = (_Float16)f1.x; hv[5] = (_Float16)f1.y;
      hv[6] = (_Float16)f1.z; hv[7] = (_Float16)f1.w;
      *(half8*)(dst + ((sg * 128 + oc * 16) ^ xo)) = hv;
    }
  }
  __syncthreads();

  floatx4 acc;
#pragma unroll
  for (int rg = 0; rg < 4; ++rg) acc[rg] = 0.f;

  const int rowb = (wid * 16 + (l & 15)) * 512;
  const int xorb = (l & 7) << 4;
  const int koffA = (l >> 4) * 16;
  const char* hTb = (const char*)hT;

  half8 a, sc;
  int prevjb;

  {
    uint32_t e0 = gtab[tbase];
    int jb = (int)(e0 & 0xFFFFu);
    a = *(const half8*)(hTb + rowb + ((jb * 2 + koffA) ^ xorb));
    half8 b = *(const half8*)(Wt + (size_t)tbase * 512 + l * 8);
    acc = mfma16(a, b, acc);
    prevjb = jb;
  }

  for (int u8 = 0; u8 < 18; ++u8) {
    uint32_t e = gtab[tbase + 1 + u8 * 8];
    int i0b = (int)(e >> 16);
    int jb = (int)(e & 0xFFFFu);
    const int ttb = tbase + 1 + u8 * 8;
    half8 bq[8];
#pragma unroll
    for (int s = 0; s < 8; ++s)
      bq[s] = *(const half8*)(Wt + (size_t)(ttb + s) * 512 + l * 8);
    if (jb != prevjb) {
      prevjb = jb;
      a = *(const half8*)(hTb + rowb + ((jb * 2 + koffA) ^ xorb));
    }
    sc = *(const half8*)(hTb + rowb + ((i0b * 2) ^ xorb));
#pragma unroll
    for (int s = 0; s < 8; ++s) {
      _Float16 sv = sc[s];
      half8 sb = {sv, sv, sv, sv, sv, sv, sv, sv};
      acc = mfma16(a * sb, bq[s], acc);
    }
  }

  float* op = part2 + (size_t)kch * 65536;
  const int r0 = rb * 128 + wid * 16 + (l >> 4) * 4;
  const int c = l & 15;
#pragma unroll
  for (int rg = 0; rg < 4; ++rg)
    op[(size_t)(r0 + rg) * 16 + c] = acc[rg];
}

// ---------------------------------------------------------------------------
extern "C" void kernel_launch(void* const* d_in, const int* in_sizes, int n_in,
                              void* d_out, int out_size, void* d_ws, size_t ws_size,
                              hipStream_t stream) {
  const float* x = (const float*)d_in[0];
  const float* W0 = (const float*)d_in[1];
  const float* b0 = (const float*)d_in[2];
  const float* W1 = (const float*)d_in[3];
  const float* b1 = (const float*)d_in[4];
  const float* W2 = (const float*)d_in[5];
  const float* b2 = (const float*)d_in[6];
  float* out = (float*)d_out;

  char* ws = (char*)d_ws;
  float* h1 = (float*)ws;                                  // 4 MB
  float* h2 = (float*)(ws + (4u << 20));                   // 4 MB
  _Float16* Wt = (_Float16*)(ws + (8u << 20));             // 19,005,440 B
  uint32_t* tab = (uint32_t*)(ws + (8u << 20) + 19005440u);
  float* part = (float*)(ws + (28u << 20));                // 8 x 4 MB partials
  float* part2 = part;                                     // reuse (2 MB)

  build_tab<<<(NTILES + 255) / 256, 256, 0, stream>>>(tab);

  // layer 0
  convert_w<<<(NTILES * 16 * 64) / 256, 256, 0, stream>>>(W0, Wt, tab, 16, 256);
  qgemm_main<<<256, 512, 0, stream>>>(x, Wt, part, tab);
  reduce_h<<<1024, 256, 0, stream>>>(part, b0, h1);
  // layer 1
  convert_w<<<(NTILES * 16 * 64) / 256, 256, 0, stream>>>(W1, Wt, tab, 16, 256);
  qgemm_main<<<256, 512, 0, stream>>>(h1, Wt, part, tab);
  reduce_h<<<1024, 256, 0, stream>>>(part, b1, h2);
  // layer 2
  convert_w<<<(NTILES * 1 * 64 + 255) / 256, 256, 0, stream>>>(W2, Wt, tab, 1, 10);
  qgemm_small<<<256, 512, 0, stream>>>(h2, Wt, part2, tab);
  reduce_out<<<160, 256, 0, stream>>>(part2, b2, out);
}